// Round 1
// baseline (637.301 us; speedup 1.0000x reference)
//
#include <hip/hip_runtime.h>
#include <math.h>

// Problem constants
#define TT 1024      // sequence length
#define DMODEL 1024
#define NHEAD 16
#define NWAVE 16
#define HDIM 64
#define NBATCH 4

// ---------------------------------------------------------------------------
// Generic 128x128-tile f32 GEMM:  C[m,n] = sum_k A[m,k] * Brow(n)[k]  (+bias)
// MODE 0: proj GEMM. N=2048. cols 0..255 Wqf, 256..511 Wkf, 512..767 Wqp,
//         768..1023 Wkp (written raw, bias added later), 1024..2047 Wv
//         (bias bv added, written transposed to vt[b,h,t,d]).
// MODE 1: out GEMM. N=1024, W0=Wo, bias=bo, writes d_out.
// ---------------------------------------------------------------------------
template <int MODE>
__device__ __forceinline__ const float* b_rowptr(
    int n, const float* W0, const float* W1, const float* W2,
    const float* W3, const float* W4)
{
    if (MODE == 1) return W0 + n * 1024;
    if (n < 256)  return W0 + n * 1024;
    if (n < 512)  return W1 + (n - 256) * 1024;
    if (n < 768)  return W2 + (n - 512) * 1024;
    if (n < 1024) return W3 + (n - 768) * 1024;
    return W4 + (n - 1024) * 1024;
}

template <int MODE>
__global__ __launch_bounds__(256)
void gemm128(const float* __restrict__ A,
             const float* __restrict__ W0, const float* __restrict__ W1,
             const float* __restrict__ W2, const float* __restrict__ W3,
             const float* __restrict__ W4,
             const float* __restrict__ bias,
             float* __restrict__ out0, float* __restrict__ out1)
{
    __shared__ float As[16][132];   // k-major, pad to 132 (16B-aligned rows)
    __shared__ float Bs[16][132];

    const int tid = threadIdx.x;           // 256 threads
    const int tx = tid & 15, ty = tid >> 4;
    const int bm = blockIdx.y * 128;
    const int bn = blockIdx.x * 128;

    float acc[8][8];
#pragma unroll
    for (int i = 0; i < 8; i++)
#pragma unroll
        for (int j = 0; j < 8; j++) acc[i][j] = 0.f;

    // each thread loads 2 float4 per matrix per K-tile
    const int r_ld = tid >> 2;             // 0..63
    const int c4   = (tid & 3) << 2;       // 0,4,8,12
    const float* arow0 = A + (size_t)(bm + r_ld) * 1024;
    const float* arow1 = A + (size_t)(bm + 64 + r_ld) * 1024;
    const float* brow0 = b_rowptr<MODE>(bn + r_ld,      W0, W1, W2, W3, W4);
    const float* brow1 = b_rowptr<MODE>(bn + 64 + r_ld, W0, W1, W2, W3, W4);

    for (int k0 = 0; k0 < 1024; k0 += 16) {
        float4 a0 = *reinterpret_cast<const float4*>(&arow0[k0 + c4]);
        float4 a1 = *reinterpret_cast<const float4*>(&arow1[k0 + c4]);
        float4 b0 = *reinterpret_cast<const float4*>(&brow0[k0 + c4]);
        float4 b1 = *reinterpret_cast<const float4*>(&brow1[k0 + c4]);
        As[c4 + 0][r_ld] = a0.x; As[c4 + 1][r_ld] = a0.y;
        As[c4 + 2][r_ld] = a0.z; As[c4 + 3][r_ld] = a0.w;
        As[c4 + 0][64 + r_ld] = a1.x; As[c4 + 1][64 + r_ld] = a1.y;
        As[c4 + 2][64 + r_ld] = a1.z; As[c4 + 3][64 + r_ld] = a1.w;
        Bs[c4 + 0][r_ld] = b0.x; Bs[c4 + 1][r_ld] = b0.y;
        Bs[c4 + 2][r_ld] = b0.z; Bs[c4 + 3][r_ld] = b0.w;
        Bs[c4 + 0][64 + r_ld] = b1.x; Bs[c4 + 1][64 + r_ld] = b1.y;
        Bs[c4 + 2][64 + r_ld] = b1.z; Bs[c4 + 3][64 + r_ld] = b1.w;
        __syncthreads();

#pragma unroll
        for (int k = 0; k < 16; k++) {
            float4 fa0 = *reinterpret_cast<const float4*>(&As[k][ty * 4]);
            float4 fa1 = *reinterpret_cast<const float4*>(&As[k][64 + ty * 4]);
            float4 fb0 = *reinterpret_cast<const float4*>(&Bs[k][tx * 4]);
            float4 fb1 = *reinterpret_cast<const float4*>(&Bs[k][64 + tx * 4]);
            float av[8] = {fa0.x, fa0.y, fa0.z, fa0.w, fa1.x, fa1.y, fa1.z, fa1.w};
            float bv[8] = {fb0.x, fb0.y, fb0.z, fb0.w, fb1.x, fb1.y, fb1.z, fb1.w};
#pragma unroll
            for (int i = 0; i < 8; i++)
#pragma unroll
                for (int j = 0; j < 8; j++)
                    acc[i][j] = fmaf(av[i], bv[j], acc[i][j]);
        }
        __syncthreads();
    }

    // epilogue
#pragma unroll
    for (int ig = 0; ig < 2; ig++) {
#pragma unroll
        for (int i = 0; i < 4; i++) {
            const int m = bm + ig * 64 + ty * 4 + i;
#pragma unroll
            for (int jg = 0; jg < 2; jg++) {
                const int n0 = bn + jg * 64 + tx * 4;
                float tmp[4];
#pragma unroll
                for (int j = 0; j < 4; j++) tmp[j] = acc[ig * 4 + i][jg * 4 + j];
                if (MODE == 1) {
#pragma unroll
                    for (int j = 0; j < 4; j++) tmp[j] += bias[n0 + j];
                    *reinterpret_cast<float4*>(&out0[(size_t)m * 1024 + n0]) =
                        *reinterpret_cast<float4*>(tmp);
                } else if (n0 < 1024) {
                    // raw qf/kf/qp/kp (bias added in norm kernel)
                    *reinterpret_cast<float4*>(&out0[(size_t)m * 1024 + n0]) =
                        *reinterpret_cast<float4*>(tmp);
                } else {
                    // v -> vt[b,h,t,d] with bias
                    const int jj = n0 - 1024;
#pragma unroll
                    for (int j = 0; j < 4; j++) tmp[j] += bias[jj + j];
                    const int h = jj >> 6, d = jj & 63;
                    const int b = m >> 10, t = m & 1023;
                    *reinterpret_cast<float4*>(
                        &out1[(((size_t)(b * 16 + h) * 1024 + t) * 64) + d]) =
                        *reinterpret_cast<float4*>(tmp);
                }
            }
        }
    }
}

// ---------------------------------------------------------------------------
// Wave transform + l2norm.  One block per (b,t) row, 256 threads = (h,w).
//   q_waves = sin(qf * t + qp); qn = q_waves / max(||q_waves||_2, eps) * NW^0.25
// Writes qn/kn in [b,h,t,w] layout.
// ---------------------------------------------------------------------------
__global__ __launch_bounds__(256)
void wave_norm(const float* __restrict__ raw,
               const float* __restrict__ bqf, const float* __restrict__ bkf,
               const float* __restrict__ bqp, const float* __restrict__ bkp,
               float* __restrict__ qn, float* __restrict__ kn)
{
    const int row = blockIdx.x;            // b*T + t
    const int b = row >> 10, t = row & 1023;
    const int tid = threadIdx.x;           // h*16 + w
    const float tf = (float)t;

    const float qf = raw[(size_t)row * 1024 + tid]        + bqf[tid];
    const float kf = raw[(size_t)row * 1024 + 256 + tid]  + bkf[tid];
    const float qp = raw[(size_t)row * 1024 + 512 + tid]  + bqp[tid];
    const float kp = raw[(size_t)row * 1024 + 768 + tid]  + bkp[tid];

    const float sq = sinf(fmaf(qf, tf, qp));
    const float sk = sinf(fmaf(kf, tf, kp));

    float nq = sq * sq, nk = sk * sk;
#pragma unroll
    for (int off = 8; off >= 1; off >>= 1) {
        nq += __shfl_xor(nq, off, 16);
        nk += __shfl_xor(nk, off, 16);
    }
    const float qv = sq * 2.0f / fmaxf(sqrtf(nq), 1e-12f);  // NW^0.25 = 2
    const float kv = sk * 2.0f / fmaxf(sqrtf(nk), 1e-12f);

    const int h = tid >> 4, w = tid & 15;
    const size_t o = ((size_t)(b * 16 + h) * 1024 + t) * 16 + w;
    qn[o] = qv;
    kn[o] = kv;
}

// ---------------------------------------------------------------------------
// Causal linear-kernel attention, 64x64 tiles.
// grid = (it=16, bh=64); block = 256 threads (16x16).
// out y[b,t,h*64+d]
// ---------------------------------------------------------------------------
__global__ __launch_bounds__(256)
void wave_attn(const float* __restrict__ qn, const float* __restrict__ kn,
               const float* __restrict__ vt, const float* __restrict__ iscale,
               float* __restrict__ y)
{
    __shared__ float qs[16][68];   // [w][t]
    __shared__ float ks[16][68];   // [w][s]
    __shared__ float Vs[64][68];   // [s][d]
    __shared__ float Sm[64][68];   // [t][s]

    const int it = blockIdx.x;
    const int bh = blockIdx.y;
    const int h = bh & 15, b = bh >> 4;
    const int t0 = it * 64;
    const int tid = threadIdx.x;
    const int tx = tid & 15, ty = tid >> 4;
    const float scale = iscale[h];

    // load q tile (64 rows x 16 w), transposed into qs[w][t]
    {
        const int r = tid >> 2, c4 = (tid & 3) << 2;
        float4 q4 = *reinterpret_cast<const float4*>(
            &qn[((size_t)bh * 1024 + t0 + r) * 16 + c4]);
        qs[c4 + 0][r] = q4.x; qs[c4 + 1][r] = q4.y;
        qs[c4 + 2][r] = q4.z; qs[c4 + 3][r] = q4.w;
    }

    float acc[4][4];
#pragma unroll
    for (int i = 0; i < 4; i++)
#pragma unroll
        for (int j = 0; j < 4; j++) acc[i][j] = 0.f;

    for (int is = 0; is <= it; is++) {
        const int s0 = is * 64;
        // load k tile transposed
        {
            const int r = tid >> 2, c4 = (tid & 3) << 2;
            float4 k4 = *reinterpret_cast<const float4*>(
                &kn[((size_t)bh * 1024 + s0 + r) * 16 + c4]);
            ks[c4 + 0][r] = k4.x; ks[c4 + 1][r] = k4.y;
            ks[c4 + 2][r] = k4.z; ks[c4 + 3][r] = k4.w;
        }
        // load V tile (64 x 64)
#pragma unroll
        for (int c = 0; c < 4; c++) {
            const int idx = tid + 256 * c;
            const int vr = idx >> 4, vc = (idx & 15) << 2;
            *reinterpret_cast<float4*>(&Vs[vr][vc]) =
                *reinterpret_cast<const float4*>(
                    &vt[((size_t)bh * 1024 + s0 + vr) * 64 + vc]);
        }
        __syncthreads();

        // scores: sc[i][j] = qn[t0+4ty+i] . kn[s0+4tx+j]
        float sc[4][4];
#pragma unroll
        for (int i = 0; i < 4; i++)
#pragma unroll
            for (int j = 0; j < 4; j++) sc[i][j] = 0.f;
#pragma unroll
        for (int w = 0; w < 16; w++) {
            float4 qv4 = *reinterpret_cast<const float4*>(&qs[w][ty * 4]);
            float4 kv4 = *reinterpret_cast<const float4*>(&ks[w][tx * 4]);
            float qa[4] = {qv4.x, qv4.y, qv4.z, qv4.w};
            float ka[4] = {kv4.x, kv4.y, kv4.z, kv4.w};
#pragma unroll
            for (int i = 0; i < 4; i++)
#pragma unroll
                for (int j = 0; j < 4; j++)
                    sc[i][j] = fmaf(qa[i], ka[j], sc[i][j]);
        }
        // elu+1 kernel, causal mask, store to LDS
#pragma unroll
        for (int i = 0; i < 4; i++) {
            const int trow = t0 + ty * 4 + i;
            float tmp[4];
#pragma unroll
            for (int j = 0; j < 4; j++) {
                const float xv = sc[i][j] * scale;
                float phi = (xv > 0.f) ? (xv + 1.0f) : expf(xv);
                if (s0 + tx * 4 + j > trow) phi = 0.f;
                tmp[j] = phi;
            }
            *reinterpret_cast<float4*>(&Sm[ty * 4 + i][tx * 4]) =
                *reinterpret_cast<float4*>(tmp);
        }
        __syncthreads();

        // PV: acc[i][j] += Sm[4ty+i][s] * Vs[s][4tx+j]
#pragma unroll 8
        for (int s = 0; s < 64; s++) {
            float4 vv4 = *reinterpret_cast<const float4*>(&Vs[s][tx * 4]);
            float va[4] = {vv4.x, vv4.y, vv4.z, vv4.w};
            float sv[4];
#pragma unroll
            for (int i = 0; i < 4; i++) sv[i] = Sm[ty * 4 + i][s];
#pragma unroll
            for (int i = 0; i < 4; i++)
#pragma unroll
                for (int j = 0; j < 4; j++)
                    acc[i][j] = fmaf(sv[i], va[j], acc[i][j]);
        }
        __syncthreads();
    }

    // epilogue: divide by sqrt(t+1), write y[b,t,h*64+d]
#pragma unroll
    for (int i = 0; i < 4; i++) {
        const int trow = t0 + ty * 4 + i;
        const float inv = 1.0f / sqrtf((float)(trow + 1));
        float tmp[4];
#pragma unroll
        for (int j = 0; j < 4; j++) tmp[j] = acc[i][j] * inv;
        *reinterpret_cast<float4*>(
            &y[((size_t)b * 1024 + trow) * 1024 + h * 64 + tx * 4]) =
            *reinterpret_cast<float4*>(tmp);
    }
}

// ---------------------------------------------------------------------------
extern "C" void kernel_launch(void* const* d_in, const int* in_sizes, int n_in,
                              void* d_out, int out_size, void* d_ws, size_t ws_size,
                              hipStream_t stream)
{
    const float* x   = (const float*)d_in[0];
    const float* Wqf = (const float*)d_in[1];
    const float* bqf = (const float*)d_in[2];
    const float* Wkf = (const float*)d_in[3];
    const float* bkf = (const float*)d_in[4];
    const float* Wqp = (const float*)d_in[5];
    const float* bqp = (const float*)d_in[6];
    const float* Wkp = (const float*)d_in[7];
    const float* bkp = (const float*)d_in[8];
    const float* Wv  = (const float*)d_in[9];
    const float* bv  = (const float*)d_in[10];
    const float* Wo  = (const float*)d_in[11];
    const float* bo  = (const float*)d_in[12];
    const float* isc = (const float*)d_in[13];
    float* out = (float*)d_out;

    char* ws = (char*)d_ws;
    float* raw = (float*)(ws);                          // 4096x1024 f32 = 16MB
    float* qn  = (float*)(ws + (16u << 20));            // 4MB
    float* kn  = (float*)(ws + (20u << 20));            // 4MB
    float* vt  = (float*)(ws + (24u << 20));            // 16MB
    float* y   = raw;                                   // reuse (raw consumed)

    // 1) fused projection GEMM: [4096,1024] x [2048,1024]^T
    gemm128<0><<<dim3(16, 32), 256, 0, stream>>>(
        x, Wqf, Wkf, Wqp, Wkp, Wv, bv, raw, vt);

    // 2) sin + l2norm
    wave_norm<<<4096, 256, 0, stream>>>(raw, bqf, bkf, bqp, bkp, qn, kn);

    // 3) causal linear attention
    wave_attn<<<dim3(16, 64), 256, 0, stream>>>(qn, kn, vt, isc, y);

    // 4) output projection
    gemm128<1><<<dim3(8, 32), 256, 0, stream>>>(
        y, Wo, nullptr, nullptr, nullptr, nullptr, bo, out, nullptr);
}

// Round 4
// 376.894 us; speedup vs baseline: 1.6909x; 1.6909x over previous
//
#include <hip/hip_runtime.h>
#include <math.h>

typedef __attribute__((ext_vector_type(8))) short bf16x8;
typedef __attribute__((ext_vector_type(4))) float f32x4;

typedef __attribute__((address_space(3))) void lds_void;
typedef __attribute__((address_space(1))) const void glb_cvoid;

__device__ __forceinline__ unsigned short f32_to_bf16(float f) {
    unsigned u = __float_as_uint(f);
    unsigned r = (u + 0x7FFFu + ((u >> 16) & 1u)) >> 16;
    return (unsigned short)r;
}
__device__ __forceinline__ float bf16_to_f32(unsigned short h) {
    return __uint_as_float(((unsigned)h) << 16);
}

// ---------------------------------------------------------------------------
// f32 -> bf16 hi (+ optional lo residual) converter. n4 = n/4 float4 groups.
// ---------------------------------------------------------------------------
__global__ __launch_bounds__(256)
void split_bf16(const float* __restrict__ src, unsigned short* __restrict__ hi,
                unsigned short* __restrict__ lo, int n4)
{
    const int i = blockIdx.x * 256 + threadIdx.x;
    if (i >= n4) return;
    float4 v = *reinterpret_cast<const float4*>(src + (size_t)i * 4);
    ushort4 h;
    h.x = f32_to_bf16(v.x); h.y = f32_to_bf16(v.y);
    h.z = f32_to_bf16(v.z); h.w = f32_to_bf16(v.w);
    *reinterpret_cast<ushort4*>(hi + (size_t)i * 4) = h;
    if (lo) {
        ushort4 l;
        l.x = f32_to_bf16(v.x - bf16_to_f32(h.x));
        l.y = f32_to_bf16(v.y - bf16_to_f32(h.y));
        l.z = f32_to_bf16(v.z - bf16_to_f32(h.z));
        l.w = f32_to_bf16(v.w - bf16_to_f32(h.w));
        *reinterpret_cast<ushort4*>(lo + (size_t)i * 4) = l;
    }
}

// ---------------------------------------------------------------------------
// bf16 MFMA GEMM: C[m,n] = sum_k A[m,k] * B[n,k]   (A,B row-major, K contig)
// Tile 128(M) x 64(N), BK=32, 256 threads = 4 waves (2x2), each wave 64x32.
// All operand rows are 1024 elements.
// MODE 0 (freq): K=3072 split-precision: segs [xh|xl|xh] x [Wh|Wh|Wl],
//                writes raw f32 [4096][1024], no bias.
// MODE 1 (v):    K=1024, +bias, writes vt[b,h,t,d] bf16 (transposed).
// MODE 2 (out):  K=1024, +bias, writes f32 [4096][1024] (d_out).
// ---------------------------------------------------------------------------
template <int MODE>
__global__ __launch_bounds__(256)
void mfma_gemm(const unsigned short* __restrict__ A0,
               const unsigned short* __restrict__ A1,
               const unsigned short* __restrict__ B0,
               const unsigned short* __restrict__ B1,
               const float* __restrict__ bias,
               float* __restrict__ outF, unsigned short* __restrict__ outH)
{
    __shared__ __attribute__((aligned(16))) unsigned short Al[128 * 32];
    __shared__ __attribute__((aligned(16))) unsigned short Bl[64 * 32];

    const int tid = threadIdx.x;
    const int w = tid >> 6, l = tid & 63;
    const int bm = blockIdx.y * 128, bn = blockIdx.x * 64;
    const int KTOT = (MODE == 0) ? 3072 : 1024;
    const int wr = w >> 1, wc = w & 1;
    const int lr = l & 15, lg = l >> 4;
    const int sr = l >> 2;             // staging row within 16-row chunk
    const int sc = (l & 3) * 8;        // staging col (8 bf16 = 16 B)

    f32x4 acc[4][2];
#pragma unroll
    for (int i = 0; i < 4; i++)
#pragma unroll
        for (int j = 0; j < 2; j++)
#pragma unroll
            for (int r = 0; r < 4; r++) acc[i][j][r] = 0.f;

    for (int k0 = 0; k0 < KTOT; k0 += 32) {
        const unsigned short* Aseg = A0;
        const unsigned short* Bseg = B0;
        int kc = k0;
        if (MODE == 0) {
            const int seg = k0 >> 10;
            kc = k0 & 1023;
            if (seg == 1) Aseg = A1;   // xl * Wh
            if (seg == 2) Bseg = B1;   // xh * Wl
        }
        // stage: A rows [w*32, w*32+32), B rows [w*16, w*16+16); 16B per lane
        __builtin_amdgcn_global_load_lds(
            (glb_cvoid*)(Aseg + (size_t)(bm + w * 32 + sr) * 1024 + kc + sc),
            (lds_void*)(&Al[(w * 32) * 32]), 16, 0, 0);
        __builtin_amdgcn_global_load_lds(
            (glb_cvoid*)(Aseg + (size_t)(bm + w * 32 + 16 + sr) * 1024 + kc + sc),
            (lds_void*)(&Al[(w * 32 + 16) * 32]), 16, 0, 0);
        __builtin_amdgcn_global_load_lds(
            (glb_cvoid*)(Bseg + (size_t)(bn + w * 16 + sr) * 1024 + kc + sc),
            (lds_void*)(&Bl[(w * 16) * 32]), 16, 0, 0);
        __syncthreads();   // staging visible (compiler drains vmcnt)

        bf16x8 af[4], bfr[2];
#pragma unroll
        for (int i = 0; i < 4; i++)
            af[i] = *reinterpret_cast<const bf16x8*>(
                &Al[(wr * 64 + i * 16 + lr) * 32 + lg * 8]);
#pragma unroll
        for (int j = 0; j < 2; j++)
            bfr[j] = *reinterpret_cast<const bf16x8*>(
                &Bl[(wc * 32 + j * 16 + lr) * 32 + lg * 8]);
#pragma unroll
        for (int i = 0; i < 4; i++)
#pragma unroll
            for (int j = 0; j < 2; j++)
                acc[i][j] = __builtin_amdgcn_mfma_f32_16x16x32_bf16(
                    af[i], bfr[j], acc[i][j], 0, 0, 0);
        __syncthreads();   // reads done before next-iter overwrite
    }

    // epilogue: C/D layout col = lane&15, row = (lane>>4)*4 + reg
#pragma unroll
    for (int i = 0; i < 4; i++) {
#pragma unroll
        for (int j = 0; j < 2; j++) {
#pragma unroll
            for (int r = 0; r < 4; r++) {
                const int row = bm + wr * 64 + i * 16 + lg * 4 + r;
                const int col = bn + wc * 32 + j * 16 + lr;
                float v = acc[i][j][r];
                if (MODE == 0) {
                    outF[(size_t)row * 1024 + col] = v;
                } else if (MODE == 1) {
                    v += bias[col];
                    const int hh = col >> 6, d = col & 63;
                    const int b = row >> 10, t = row & 1023;
                    outH[(((size_t)(b * 16 + hh) * 1024 + t) * 64) + d] =
                        f32_to_bf16(v);
                } else {
                    outF[(size_t)row * 1024 + col] = v + bias[col];
                }
            }
        }
    }
}

// ---------------------------------------------------------------------------
// Wave transform + l2norm.  One block per (b,t) row, 256 threads = (h,w).
// Reads raw f32 (qf,kf,qp,kp in cols 0..1023), writes qn/kn bf16 [b,h,t,w].
// ---------------------------------------------------------------------------
__global__ __launch_bounds__(256)
void wave_norm(const float* __restrict__ raw,
               const float* __restrict__ bqf, const float* __restrict__ bkf,
               const float* __restrict__ bqp, const float* __restrict__ bkp,
               unsigned short* __restrict__ qn, unsigned short* __restrict__ kn)
{
    const int row = blockIdx.x;            // b*T + t
    const int b = row >> 10, t = row & 1023;
    const int tid = threadIdx.x;           // h*16 + w
    const float tf = (float)t;

    const float qf = raw[(size_t)row * 1024 + tid]        + bqf[tid];
    const float kf = raw[(size_t)row * 1024 + 256 + tid]  + bkf[tid];
    const float qp = raw[(size_t)row * 1024 + 512 + tid]  + bqp[tid];
    const float kp = raw[(size_t)row * 1024 + 768 + tid]  + bkp[tid];

    const float sq = sinf(fmaf(qf, tf, qp));
    const float sk = sinf(fmaf(kf, tf, kp));

    float nq = sq * sq, nk = sk * sk;
#pragma unroll
    for (int off = 8; off >= 1; off >>= 1) {
        nq += __shfl_xor(nq, off, 16);
        nk += __shfl_xor(nk, off, 16);
    }
    const float qv = sq * 2.0f / fmaxf(sqrtf(nq), 1e-12f);  // NW^0.25 = 2
    const float kv = sk * 2.0f / fmaxf(sqrtf(nk), 1e-12f);

    const int h = tid >> 4, ww = tid & 15;
    const size_t o = ((size_t)(b * 16 + h) * 1024 + t) * 16 + ww;
    qn[o] = f32_to_bf16(qv);
    kn[o] = f32_to_bf16(kv);
}

// ---------------------------------------------------------------------------
// Causal linear-kernel attention, 64x64 tiles (f32 SIMT compute, bf16 I/O).
// grid = (it=16, bh=64); block = 256 threads (16x16). Writes y bf16.
// ---------------------------------------------------------------------------
__global__ __launch_bounds__(256)
void wave_attn(const unsigned short* __restrict__ qn,
               const unsigned short* __restrict__ kn,
               const unsigned short* __restrict__ vt,
               const float* __restrict__ iscale,
               unsigned short* __restrict__ y)
{
    __shared__ float qs[16][68];   // [w][t]
    __shared__ float ks[16][68];   // [w][s]
    __shared__ float Vs[64][68];   // [s][d]
    __shared__ float Sm[64][68];   // [t][s]

    const int it = blockIdx.x;
    const int bh = blockIdx.y;
    const int h = bh & 15, b = bh >> 4;
    const int t0 = it * 64;
    const int tid = threadIdx.x;
    const int tx = tid & 15, ty = tid >> 4;
    const float scale = iscale[h];

    {
        const int r = tid >> 2, c4 = (tid & 3) << 2;
        ushort4 q4 = *reinterpret_cast<const ushort4*>(
            &qn[((size_t)bh * 1024 + t0 + r) * 16 + c4]);
        qs[c4 + 0][r] = bf16_to_f32(q4.x); qs[c4 + 1][r] = bf16_to_f32(q4.y);
        qs[c4 + 2][r] = bf16_to_f32(q4.z); qs[c4 + 3][r] = bf16_to_f32(q4.w);
    }

    float acc[4][4];
#pragma unroll
    for (int i = 0; i < 4; i++)
#pragma unroll
        for (int j = 0; j < 4; j++) acc[i][j] = 0.f;

    for (int is = 0; is <= it; is++) {
        const int s0 = is * 64;
        {
            const int r = tid >> 2, c4 = (tid & 3) << 2;
            ushort4 k4 = *reinterpret_cast<const ushort4*>(
                &kn[((size_t)bh * 1024 + s0 + r) * 16 + c4]);
            ks[c4 + 0][r] = bf16_to_f32(k4.x); ks[c4 + 1][r] = bf16_to_f32(k4.y);
            ks[c4 + 2][r] = bf16_to_f32(k4.z); ks[c4 + 3][r] = bf16_to_f32(k4.w);
        }
#pragma unroll
        for (int c = 0; c < 4; c++) {
            const int idx = tid + 256 * c;
            const int vr = idx >> 4, vc = (idx & 15) << 2;
            ushort4 v4 = *reinterpret_cast<const ushort4*>(
                &vt[((size_t)bh * 1024 + s0 + vr) * 64 + vc]);
            Vs[vr][vc + 0] = bf16_to_f32(v4.x); Vs[vr][vc + 1] = bf16_to_f32(v4.y);
            Vs[vr][vc + 2] = bf16_to_f32(v4.z); Vs[vr][vc + 3] = bf16_to_f32(v4.w);
        }
        __syncthreads();

        float sc[4][4];
#pragma unroll
        for (int i = 0; i < 4; i++)
#pragma unroll
            for (int j = 0; j < 4; j++) sc[i][j] = 0.f;
#pragma unroll
        for (int w = 0; w < 16; w++) {
            float4 qv4 = *reinterpret_cast<const float4*>(&qs[w][ty * 4]);
            float4 kv4 = *reinterpret_cast<const float4*>(&ks[w][tx * 4]);
            float qa[4] = {qv4.x, qv4.y, qv4.z, qv4.w};
            float ka[4] = {kv4.x, kv4.y, kv4.z, kv4.w};
#pragma unroll
            for (int i = 0; i < 4; i++)
#pragma unroll
                for (int j = 0; j < 4; j++)
                    sc[i][j] = fmaf(qa[i], ka[j], sc[i][j]);
        }
#pragma unroll
        for (int i = 0; i < 4; i++) {
            const int trow = t0 + ty * 4 + i;
            float tmp[4];
#pragma unroll
            for (int j = 0; j < 4; j++) {
                const float xv = sc[i][j] * scale;
                float phi = (xv > 0.f) ? (xv + 1.0f) : expf(xv);
                if (s0 + tx * 4 + j > trow) phi = 0.f;
                tmp[j] = phi;
            }
            *reinterpret_cast<float4*>(&Sm[ty * 4 + i][tx * 4]) =
                *reinterpret_cast<float4*>(tmp);
        }
        __syncthreads();

#pragma unroll 8
        for (int s = 0; s < 64; s++) {
            float4 vv4 = *reinterpret_cast<const float4*>(&Vs[s][tx * 4]);
            float va[4] = {vv4.x, vv4.y, vv4.z, vv4.w};
            float sv[4];
#pragma unroll
            for (int i = 0; i < 4; i++) sv[i] = Sm[ty * 4 + i][s];
#pragma unroll
            for (int i = 0; i < 4; i++)
#pragma unroll
                for (int j = 0; j < 4; j++)
                    acc[i][j] = fmaf(sv[i], va[j], acc[i][j]);
        }
        __syncthreads();
    }

#pragma unroll
    for (int i = 0; i < 4; i++) {
        const int trow = t0 + ty * 4 + i;
        const float inv = 1.0f / sqrtf((float)(trow + 1));
        ushort4 o4;
        o4.x = f32_to_bf16(acc[i][0] * inv);
        o4.y = f32_to_bf16(acc[i][1] * inv);
        o4.z = f32_to_bf16(acc[i][2] * inv);
        o4.w = f32_to_bf16(acc[i][3] * inv);
        *reinterpret_cast<ushort4*>(
            &y[((size_t)b * 1024 + trow) * 1024 + h * 64 + tx * 4]) = o4;
    }
}

// ---------------------------------------------------------------------------
extern "C" void kernel_launch(void* const* d_in, const int* in_sizes, int n_in,
                              void* d_out, int out_size, void* d_ws, size_t ws_size,
                              hipStream_t stream)
{
    const float* x   = (const float*)d_in[0];
    const float* Wqf = (const float*)d_in[1];
    const float* bqf = (const float*)d_in[2];
    const float* Wkf = (const float*)d_in[3];
    const float* bkf = (const float*)d_in[4];
    const float* Wqp = (const float*)d_in[5];
    const float* bqp = (const float*)d_in[6];
    const float* Wkp = (const float*)d_in[7];
    const float* bkp = (const float*)d_in[8];
    const float* Wv  = (const float*)d_in[9];
    const float* bv  = (const float*)d_in[10];
    const float* Wo  = (const float*)d_in[11];
    const float* bo  = (const float*)d_in[12];
    const float* isc = (const float*)d_in[13];
    float* out = (float*)d_out;

    // workspace plan (38 MB, ZERO live-range overlaps — r3 fix):
    //   [ 0,16) raw f32 (freq out)      -> after wave_norm: ybf bf16 [0,8)
    //   [16,24) xh bf16                    (live until v GEMM done)
    //   [24,32) xl bf16                 -> after freq GEMM: vt bf16
    //   [32,34) WfH bf16                -> after freq GEMM: WvH, then WoH
    //   [34,36) WfL bf16                -> after freq GEMM: qn bf16
    //   [36,38) kn bf16
    char* ws = (char*)d_ws;
    float*          raw = (float*)(ws);
    unsigned short* ybf = (unsigned short*)(ws);
    unsigned short* xh  = (unsigned short*)(ws + (16u << 20));
    unsigned short* xl  = (unsigned short*)(ws + (24u << 20));
    unsigned short* vt  = (unsigned short*)(ws + (24u << 20));
    unsigned short* WfH = (unsigned short*)(ws + (32u << 20));
    unsigned short* WfL = (unsigned short*)(ws + (34u << 20));
    unsigned short* qn  = (unsigned short*)(ws + (34u << 20));
    unsigned short* kn  = (unsigned short*)(ws + (36u << 20));
    unsigned short* WvH = WfH;   // slot reuse after freq GEMM
    unsigned short* WoH = WfH;   // slot reuse after v GEMM

    // conversions for the split-precision freq GEMM
    split_bf16<<<4096, 256, 0, stream>>>(x, xh, xl, 1048576);
    split_bf16<<<256, 256, 0, stream>>>(Wqf, WfH + 0,      WfL + 0,      65536);
    split_bf16<<<256, 256, 0, stream>>>(Wkf, WfH + 262144, WfL + 262144, 65536);
    split_bf16<<<256, 256, 0, stream>>>(Wqp, WfH + 524288, WfL + 524288, 65536);
    split_bf16<<<256, 256, 0, stream>>>(Wkp, WfH + 786432, WfL + 786432, 65536);

    // 1) freq/phase projections, split-precision K=3072 -> raw f32
    mfma_gemm<0><<<dim3(16, 32), 256, 0, stream>>>(
        xh, xl, WfH, WfL, nullptr, raw, nullptr);

    // 2) v projection (plain bf16) -> vt bf16 [b,h,t,d]  (vt overlays dead xl)
    split_bf16<<<1024, 256, 0, stream>>>(Wv, WvH, nullptr, 262144);
    mfma_gemm<1><<<dim3(16, 32), 256, 0, stream>>>(
        xh, nullptr, WvH, nullptr, bv, nullptr, vt);

    // 3) sin + l2norm -> qn (overlays dead WfL) / kn
    wave_norm<<<4096, 256, 0, stream>>>(raw, bqf, bkf, bqp, bkp, qn, kn);

    // 4) causal linear attention -> ybf bf16 (overlays dead raw)
    wave_attn<<<dim3(16, 64), 256, 0, stream>>>(qn, kn, vt, isc, ybf);

    // 5) output projection -> d_out f32
    split_bf16<<<1024, 256, 0, stream>>>(Wo, WoH, nullptr, 262144);
    mfma_gemm<2><<<dim3(16, 32), 256, 0, stream>>>(
        ybf, nullptr, WoH, nullptr, bo, out, nullptr);
}

// Round 5
// 295.500 us; speedup vs baseline: 2.1567x; 1.2754x over previous
//
#include <hip/hip_runtime.h>
#include <math.h>

typedef __attribute__((ext_vector_type(8))) short bf16x8;
typedef __attribute__((ext_vector_type(4))) float f32x4;
typedef __attribute__((ext_vector_type(4))) int i32x4;

typedef __attribute__((address_space(3))) void lds_void;
typedef __attribute__((address_space(1))) const void glb_cvoid;

__device__ __forceinline__ unsigned short f32_to_bf16(float f) {
    unsigned u = __float_as_uint(f);
    unsigned r = (u + 0x7FFFu + ((u >> 16) & 1u)) >> 16;
    return (unsigned short)r;
}
__device__ __forceinline__ float bf16_to_f32(unsigned short h) {
    return __uint_as_float(((unsigned)h) << 16);
}

// ---------------------------------------------------------------------------
// f32 -> bf16 hi (+ optional lo residual) converter. n4 = n/4 float4 groups.
// ---------------------------------------------------------------------------
__global__ __launch_bounds__(256)
void split_bf16(const float* __restrict__ src, unsigned short* __restrict__ hi,
                unsigned short* __restrict__ lo, int n4)
{
    const int i = blockIdx.x * 256 + threadIdx.x;
    if (i >= n4) return;
    float4 v = *reinterpret_cast<const float4*>(src + (size_t)i * 4);
    ushort4 h;
    h.x = f32_to_bf16(v.x); h.y = f32_to_bf16(v.y);
    h.z = f32_to_bf16(v.z); h.w = f32_to_bf16(v.w);
    *reinterpret_cast<ushort4*>(hi + (size_t)i * 4) = h;
    if (lo) {
        ushort4 l;
        l.x = f32_to_bf16(v.x - bf16_to_f32(h.x));
        l.y = f32_to_bf16(v.y - bf16_to_f32(h.y));
        l.z = f32_to_bf16(v.z - bf16_to_f32(h.z));
        l.w = f32_to_bf16(v.w - bf16_to_f32(h.w));
        *reinterpret_cast<ushort4*>(lo + (size_t)i * 4) = l;
    }
}

// ---------------------------------------------------------------------------
// bf16 MFMA GEMM: C[m,n] = sum_k A[m,k] * B[n,k]   (A,B row-major, K contig)
// Tile 128(M) x 64(N), BK=32, 256 threads = 4 waves (2x2), each wave 64x32.
// MODE 0 (freq): K=3072 split-precision, writes raw f32.
// MODE 1 (v):    K=1024, +bias, writes vtt[b,h,d,t] bf16 (d-major!).
// MODE 2 (out):  K=1024, +bias, writes f32 (d_out).
// ---------------------------------------------------------------------------
template <int MODE>
__global__ __launch_bounds__(256)
void mfma_gemm(const unsigned short* __restrict__ A0,
               const unsigned short* __restrict__ A1,
               const unsigned short* __restrict__ B0,
               const unsigned short* __restrict__ B1,
               const float* __restrict__ bias,
               float* __restrict__ outF, unsigned short* __restrict__ outH)
{
    __shared__ __attribute__((aligned(16))) unsigned short Al[128 * 32];
    __shared__ __attribute__((aligned(16))) unsigned short Bl[64 * 32];

    const int tid = threadIdx.x;
    const int w = tid >> 6, l = tid & 63;
    const int bm = blockIdx.y * 128, bn = blockIdx.x * 64;
    const int KTOT = (MODE == 0) ? 3072 : 1024;
    const int wr = w >> 1, wc = w & 1;
    const int lr = l & 15, lg = l >> 4;
    const int sr = l >> 2;             // staging row within 16-row chunk
    const int sc = (l & 3) * 8;        // staging col (8 bf16 = 16 B)

    f32x4 acc[4][2];
#pragma unroll
    for (int i = 0; i < 4; i++)
#pragma unroll
        for (int j = 0; j < 2; j++)
#pragma unroll
            for (int r = 0; r < 4; r++) acc[i][j][r] = 0.f;

    for (int k0 = 0; k0 < KTOT; k0 += 32) {
        const unsigned short* Aseg = A0;
        const unsigned short* Bseg = B0;
        int kc = k0;
        if (MODE == 0) {
            const int seg = k0 >> 10;
            kc = k0 & 1023;
            if (seg == 1) Aseg = A1;   // xl * Wh
            if (seg == 2) Bseg = B1;   // xh * Wl
        }
        __builtin_amdgcn_global_load_lds(
            (glb_cvoid*)(Aseg + (size_t)(bm + w * 32 + sr) * 1024 + kc + sc),
            (lds_void*)(&Al[(w * 32) * 32]), 16, 0, 0);
        __builtin_amdgcn_global_load_lds(
            (glb_cvoid*)(Aseg + (size_t)(bm + w * 32 + 16 + sr) * 1024 + kc + sc),
            (lds_void*)(&Al[(w * 32 + 16) * 32]), 16, 0, 0);
        __builtin_amdgcn_global_load_lds(
            (glb_cvoid*)(Bseg + (size_t)(bn + w * 16 + sr) * 1024 + kc + sc),
            (lds_void*)(&Bl[(w * 16) * 32]), 16, 0, 0);
        __syncthreads();

        bf16x8 af[4], bfr[2];
#pragma unroll
        for (int i = 0; i < 4; i++)
            af[i] = *reinterpret_cast<const bf16x8*>(
                &Al[(wr * 64 + i * 16 + lr) * 32 + lg * 8]);
#pragma unroll
        for (int j = 0; j < 2; j++)
            bfr[j] = *reinterpret_cast<const bf16x8*>(
                &Bl[(wc * 32 + j * 16 + lr) * 32 + lg * 8]);
#pragma unroll
        for (int i = 0; i < 4; i++)
#pragma unroll
            for (int j = 0; j < 2; j++)
                acc[i][j] = __builtin_amdgcn_mfma_f32_16x16x32_bf16(
                    af[i], bfr[j], acc[i][j], 0, 0, 0);
        __syncthreads();
    }

    // epilogue: C/D layout col = lane&15, row = (lane>>4)*4 + reg
#pragma unroll
    for (int i = 0; i < 4; i++) {
#pragma unroll
        for (int j = 0; j < 2; j++) {
#pragma unroll
            for (int r = 0; r < 4; r++) {
                const int row = bm + wr * 64 + i * 16 + lg * 4 + r;
                const int col = bn + wc * 32 + j * 16 + lr;
                float v = acc[i][j][r];
                if (MODE == 0) {
                    outF[(size_t)row * 1024 + col] = v;
                } else if (MODE == 1) {
                    v += bias[col];
                    const int hh = col >> 6, d = col & 63;
                    const int b = row >> 10, t = row & 1023;
                    // d-major: vtt[b,h,d,t]
                    outH[(((size_t)(b * 16 + hh) * 64 + d) * 1024) + t] =
                        f32_to_bf16(v);
                } else {
                    outF[(size_t)row * 1024 + col] = v + bias[col];
                }
            }
        }
    }
}

// ---------------------------------------------------------------------------
// Wave transform + l2norm.  One block per (b,t) row, 256 threads = (h,w).
// ---------------------------------------------------------------------------
__global__ __launch_bounds__(256)
void wave_norm(const float* __restrict__ raw,
               const float* __restrict__ bqf, const float* __restrict__ bkf,
               const float* __restrict__ bqp, const float* __restrict__ bkp,
               unsigned short* __restrict__ qn, unsigned short* __restrict__ kn)
{
    const int row = blockIdx.x;            // b*T + t
    const int b = row >> 10, t = row & 1023;
    const int tid = threadIdx.x;           // h*16 + w
    const float tf = (float)t;

    const float qf = raw[(size_t)row * 1024 + tid]        + bqf[tid];
    const float kf = raw[(size_t)row * 1024 + 256 + tid]  + bkf[tid];
    const float qp = raw[(size_t)row * 1024 + 512 + tid]  + bqp[tid];
    const float kp = raw[(size_t)row * 1024 + 768 + tid]  + bkp[tid];

    const float sq = sinf(fmaf(qf, tf, qp));
    const float sk = sinf(fmaf(kf, tf, kp));

    float nq = sq * sq, nk = sk * sk;
#pragma unroll
    for (int off = 8; off >= 1; off >>= 1) {
        nq += __shfl_xor(nq, off, 16);
        nk += __shfl_xor(nk, off, 16);
    }
    const float qv = sq * 2.0f / fmaxf(sqrtf(nq), 1e-12f);  // NW^0.25 = 2
    const float kv = sk * 2.0f / fmaxf(sqrtf(nk), 1e-12f);

    const int h = tid >> 4, ww = tid & 15;
    const size_t o = ((size_t)(b * 16 + h) * 1024 + t) * 16 + ww;
    qn[o] = f32_to_bf16(qv);
    kn[o] = f32_to_bf16(kv);
}

// ---------------------------------------------------------------------------
// MFMA causal linear attention. grid (it=16, bh=64), 256 thr = 4 indep waves.
// Wave owns 16 q-rows [t0w, t0w+16). No LDS, no barriers.
//   S^T = mfma(K-frag, Q-frag)  (K=32, w padded 16->32)
//   P = elu(S*scale)+1, causal-masked, bf16 via cvt_pk
//   transpose to A-frag via ds_bpermute (in-wave)
//   O += mfma(P-frag, V^T-frag)  over 2 k-steps, 4 d-blocks
// ---------------------------------------------------------------------------
__global__ __launch_bounds__(256)
void wave_attn_mfma(const unsigned short* __restrict__ qn,
                    const unsigned short* __restrict__ kn,
                    const unsigned short* __restrict__ vtt,
                    const float* __restrict__ iscale,
                    unsigned short* __restrict__ y)
{
    const int it = blockIdx.x, bh = blockIdx.y;
    const int h = bh & 15, b = bh >> 4;
    const int tid = threadIdx.x;
    const int wq = tid >> 6;          // wave 0..3
    const int l = tid & 63;
    const int lt = l & 15;            // lane "column"
    const int gl = l >> 4;            // lane group 0..3
    const int t0w = it * 64 + wq * 16;
    const float scale = iscale[h];
    const int tmine = t0w + lt;       // t index this lane represents in S^T

    const bf16x8 zero8 = {0, 0, 0, 0, 0, 0, 0, 0};
    const f32x4 zf = {0.f, 0.f, 0.f, 0.f};

    // Q fragment (B operand): col t = lt, k = w in [gl*8, gl*8+8), gl<2 real
    bf16x8 bq = zero8;
    if (gl < 2)
        bq = *reinterpret_cast<const bf16x8*>(
            &qn[((size_t)bh * 1024 + t0w + lt) * 16 + gl * 8]);

    f32x4 o[4];
#pragma unroll
    for (int jd = 0; jd < 4; jd++) o[jd] = zf;

    // bpermute source lanes: (2*(gl&1)+c)*16 + lt, c=0,1 (byte addrs)
    const int addr0 = ((2 * (gl & 1)) * 16 + lt) * 4;
    const int addr1 = addr0 + 64;
    const bool hi = ((gl >> 1) & 1) != 0;

    for (int is = 0; is <= it; is++) {
        const int s0 = is * 64;

        // ---- QK^T: S^T[s 64][t 16] via 4 mfma (A = K-frag) ----
        f32x4 st[4];
#pragma unroll
        for (int js = 0; js < 4; js++) {
            bf16x8 ak = zero8;
            if (gl < 2)
                ak = *reinterpret_cast<const bf16x8*>(
                    &kn[((size_t)bh * 1024 + s0 + js * 16 + lt) * 16 + gl * 8]);
            st[js] = __builtin_amdgcn_mfma_f32_16x16x32_bf16(ak, bq, zf, 0, 0, 0);
        }

        // ---- elu+1, mask, pack to bf16 pairs ----
        // lane holds S[t = tmine][s = s0 + js*16 + gl*4 + r]
        int pk[4][2];
#pragma unroll
        for (int js = 0; js < 4; js++) {
            float p[4];
#pragma unroll
            for (int r = 0; r < 4; r++) {
                const int s = s0 + js * 16 + gl * 4 + r;
                const float xv = st[js][r] * scale;
                const float phi = (xv > 0.f) ? (xv + 1.0f) : __expf(xv);
                p[r] = (s <= tmine) ? phi : 0.f;
            }
            asm("v_cvt_pk_bf16_f32 %0, %1, %2"
                : "=v"(pk[js][0]) : "v"(p[0]), "v"(p[1]));
            asm("v_cvt_pk_bf16_f32 %0, %1, %2"
                : "=v"(pk[js][1]) : "v"(p[2]), "v"(p[3]));
        }

        // ---- in-wave transpose: gather A-frags of P (row t=lt, k=s) ----
        int rg[4][2][2];
#pragma unroll
        for (int js = 0; js < 4; js++)
#pragma unroll
            for (int sl = 0; sl < 2; sl++) {
                rg[js][sl][0] = __builtin_amdgcn_ds_bpermute(addr0, pk[js][sl]);
                rg[js][sl][1] = __builtin_amdgcn_ds_bpermute(addr1, pk[js][sl]);
            }

        // ---- PV: O[t][d] += P[t][s] V[s][d], K=64 = 2 steps ----
#pragma unroll
        for (int ks = 0; ks < 2; ks++) {
            i32x4 au;
#pragma unroll
            for (int c = 0; c < 2; c++)
#pragma unroll
                for (int sl = 0; sl < 2; sl++)
                    au[2 * c + sl] = hi ? rg[2 * ks + 1][sl][c]
                                        : rg[2 * ks][sl][c];
            const bf16x8 pa = __builtin_bit_cast(bf16x8, au);
#pragma unroll
            for (int jd = 0; jd < 4; jd++) {
                const bf16x8 bv = *reinterpret_cast<const bf16x8*>(
                    &vtt[((size_t)(bh * 64 + jd * 16 + lt)) * 1024 +
                         s0 + ks * 32 + gl * 8]);
                o[jd] = __builtin_amdgcn_mfma_f32_16x16x32_bf16(
                    pa, bv, o[jd], 0, 0, 0);
            }
        }
    }

    // ---- epilogue: /sqrt(t+1), write y[b,t,h*64+d] ----
#pragma unroll
    for (int r = 0; r < 4; r++) {
        const int t = t0w + gl * 4 + r;
        const float inv = rsqrtf((float)(t + 1));
#pragma unroll
        for (int jd = 0; jd < 4; jd++) {
            const int d = jd * 16 + lt;
            y[((size_t)b * 1024 + t) * 1024 + h * 64 + d] =
                f32_to_bf16(o[jd][r] * inv);
        }
    }
}

// ---------------------------------------------------------------------------
extern "C" void kernel_launch(void* const* d_in, const int* in_sizes, int n_in,
                              void* d_out, int out_size, void* d_ws, size_t ws_size,
                              hipStream_t stream)
{
    const float* x   = (const float*)d_in[0];
    const float* Wqf = (const float*)d_in[1];
    const float* bqf = (const float*)d_in[2];
    const float* Wkf = (const float*)d_in[3];
    const float* bkf = (const float*)d_in[4];
    const float* Wqp = (const float*)d_in[5];
    const float* bqp = (const float*)d_in[6];
    const float* Wkp = (const float*)d_in[7];
    const float* bkp = (const float*)d_in[8];
    const float* Wv  = (const float*)d_in[9];
    const float* bv  = (const float*)d_in[10];
    const float* Wo  = (const float*)d_in[11];
    const float* bo  = (const float*)d_in[12];
    const float* isc = (const float*)d_in[13];
    float* out = (float*)d_out;

    // workspace plan (38 MB, zero live-range overlaps — as round 4):
    //   [ 0,16) raw f32 (freq out)      -> after wave_norm: ybf bf16 [0,8)
    //   [16,24) xh bf16                    (live until v GEMM done)
    //   [24,32) xl bf16                 -> after freq GEMM: vtt bf16 [b,h,d,t]
    //   [32,34) WfH bf16                -> after freq GEMM: WvH, then WoH
    //   [34,36) WfL bf16                -> after freq GEMM: qn bf16
    //   [36,38) kn bf16
    char* ws = (char*)d_ws;
    float*          raw = (float*)(ws);
    unsigned short* ybf = (unsigned short*)(ws);
    unsigned short* xh  = (unsigned short*)(ws + (16u << 20));
    unsigned short* xl  = (unsigned short*)(ws + (24u << 20));
    unsigned short* vtt = (unsigned short*)(ws + (24u << 20));
    unsigned short* WfH = (unsigned short*)(ws + (32u << 20));
    unsigned short* WfL = (unsigned short*)(ws + (34u << 20));
    unsigned short* qn  = (unsigned short*)(ws + (34u << 20));
    unsigned short* kn  = (unsigned short*)(ws + (36u << 20));
    unsigned short* WvH = WfH;   // slot reuse after freq GEMM
    unsigned short* WoH = WfH;   // slot reuse after v GEMM

    // conversions for the split-precision freq GEMM
    split_bf16<<<4096, 256, 0, stream>>>(x, xh, xl, 1048576);
    split_bf16<<<256, 256, 0, stream>>>(Wqf, WfH + 0,      WfL + 0,      65536);
    split_bf16<<<256, 256, 0, stream>>>(Wkf, WfH + 262144, WfL + 262144, 65536);
    split_bf16<<<256, 256, 0, stream>>>(Wqp, WfH + 524288, WfL + 524288, 65536);
    split_bf16<<<256, 256, 0, stream>>>(Wkp, WfH + 786432, WfL + 786432, 65536);

    // 1) freq/phase projections, split-precision K=3072 -> raw f32
    mfma_gemm<0><<<dim3(16, 32), 256, 0, stream>>>(
        xh, xl, WfH, WfL, nullptr, raw, nullptr);

    // 2) v projection -> vtt bf16 [b,h,d,t]  (overlays dead xl)
    split_bf16<<<1024, 256, 0, stream>>>(Wv, WvH, nullptr, 262144);
    mfma_gemm<1><<<dim3(16, 32), 256, 0, stream>>>(
        xh, nullptr, WvH, nullptr, bv, nullptr, vtt);

    // 3) sin + l2norm -> qn (overlays dead WfL) / kn
    wave_norm<<<4096, 256, 0, stream>>>(raw, bqf, bkf, bqp, bkp, qn, kn);

    // 4) MFMA causal linear attention -> ybf bf16 (overlays dead raw)
    wave_attn_mfma<<<dim3(16, 64), 256, 0, stream>>>(qn, kn, vtt, isc, ybf);

    // 5) output projection -> d_out f32
    split_bf16<<<1024, 256, 0, stream>>>(Wo, WoH, nullptr, 262144);
    mfma_gemm<2><<<dim3(16, 32), 256, 0, stream>>>(
        ybf, nullptr, WoH, nullptr, bo, out, nullptr);
}

// Round 6
// 227.938 us; speedup vs baseline: 2.7959x; 1.2964x over previous
//
#include <hip/hip_runtime.h>
#include <math.h>

typedef __attribute__((ext_vector_type(8))) short bf16x8;
typedef __attribute__((ext_vector_type(4))) float f32x4;
typedef __attribute__((ext_vector_type(4))) int i32x4;

typedef __attribute__((address_space(3))) void lds_void;
typedef __attribute__((address_space(1))) const void glb_cvoid;

__device__ __forceinline__ unsigned short f32_to_bf16(float f) {
    unsigned u = __float_as_uint(f);
    unsigned r = (u + 0x7FFFu + ((u >> 16) & 1u)) >> 16;
    return (unsigned short)r;
}
__device__ __forceinline__ float bf16_to_f32(unsigned short h) {
    return __uint_as_float(((unsigned)h) << 16);
}

// ---------------------------------------------------------------------------
// f32 -> bf16 hi (+ optional lo residual) converter. n4 = n/4 float4 groups.
// ---------------------------------------------------------------------------
__global__ __launch_bounds__(256)
void split_bf16(const float* __restrict__ src, unsigned short* __restrict__ hi,
                unsigned short* __restrict__ lo, int n4)
{
    const int i = blockIdx.x * 256 + threadIdx.x;
    if (i >= n4) return;
    float4 v = *reinterpret_cast<const float4*>(src + (size_t)i * 4);
    ushort4 h;
    h.x = f32_to_bf16(v.x); h.y = f32_to_bf16(v.y);
    h.z = f32_to_bf16(v.z); h.w = f32_to_bf16(v.w);
    *reinterpret_cast<ushort4*>(hi + (size_t)i * 4) = h;
    if (lo) {
        ushort4 l;
        l.x = f32_to_bf16(v.x - bf16_to_f32(h.x));
        l.y = f32_to_bf16(v.y - bf16_to_f32(h.y));
        l.z = f32_to_bf16(v.z - bf16_to_f32(h.z));
        l.w = f32_to_bf16(v.w - bf16_to_f32(h.w));
        *reinterpret_cast<ushort4*>(lo + (size_t)i * 4) = l;
    }
}

// Fused hi+lo split of the four 256x1024 freq/phase weights (one launch).
__global__ __launch_bounds__(256)
void split4_bf16(const float* __restrict__ W0, const float* __restrict__ W1,
                 const float* __restrict__ W2, const float* __restrict__ W3,
                 unsigned short* __restrict__ hi, unsigned short* __restrict__ lo)
{
    const int i = blockIdx.x * 256 + threadIdx.x;   // 0..262143 (float4 units)
    const int sel = i >> 16, j = i & 65535;
    const float* W = (sel == 0) ? W0 : (sel == 1) ? W1 : (sel == 2) ? W2 : W3;
    float4 v = *reinterpret_cast<const float4*>(W + (size_t)j * 4);
    ushort4 h, l;
    h.x = f32_to_bf16(v.x); h.y = f32_to_bf16(v.y);
    h.z = f32_to_bf16(v.z); h.w = f32_to_bf16(v.w);
    l.x = f32_to_bf16(v.x - bf16_to_f32(h.x));
    l.y = f32_to_bf16(v.y - bf16_to_f32(h.y));
    l.z = f32_to_bf16(v.z - bf16_to_f32(h.z));
    l.w = f32_to_bf16(v.w - bf16_to_f32(h.w));
    const size_t o = (size_t)sel * 262144 + (size_t)j * 4;
    *reinterpret_cast<ushort4*>(hi + o) = h;
    *reinterpret_cast<ushort4*>(lo + o) = l;
}

// ---------------------------------------------------------------------------
// bf16 MFMA GEMM: C[m,n] = sum_k A[m,k] * B[n,k]   (A,B row-major, K contig)
// Tile 128(M) x 64(N), BK=64, 256 threads = 4 waves (2x2), each wave 64x32.
// LDS XOR-swizzle (16B slot ^ row&7) applied on BOTH sides: linear
// global_load_lds dest + inverse-swizzled GLOBAL source + swizzled ds_read
// (rule #21). Kills the 8-way bank conflict of the 128B-row layout.
// MODE 0 (freq): K=3072 split-precision, writes raw f32.
// MODE 1 (v):    K=1024, +bias, writes vtt[b,h,d,t] bf16 (d-major!).
// MODE 2 (out):  K=1024, +bias, writes f32 (d_out).
// ---------------------------------------------------------------------------
template <int MODE>
__global__ __launch_bounds__(256)
void mfma_gemm(const unsigned short* __restrict__ A0,
               const unsigned short* __restrict__ A1,
               const unsigned short* __restrict__ B0,
               const unsigned short* __restrict__ B1,
               const float* __restrict__ bias,
               float* __restrict__ outF, unsigned short* __restrict__ outH)
{
    __shared__ __attribute__((aligned(16))) unsigned short Al[128 * 64];
    __shared__ __attribute__((aligned(16))) unsigned short Bl[64 * 64];

    const int tid = threadIdx.x;
    const int w = tid >> 6, l = tid & 63;
    const int bm = blockIdx.y * 128, bn = blockIdx.x * 64;
    const int KTOT = (MODE == 0) ? 3072 : 1024;
    const int wr = w >> 1, wc = w & 1;
    const int lr = l & 15, lg = l >> 4;
    const int r8 = l >> 3;            // staging row within 8-row chunk (0..7)
    const int c8 = l & 7;             // 16B slot within 128B row (0..7)
    const int csw = (c8 ^ r8) << 3;   // inverse-swizzled global col (elements)

    f32x4 acc[4][2];
#pragma unroll
    for (int i = 0; i < 4; i++)
#pragma unroll
        for (int j = 0; j < 2; j++)
#pragma unroll
            for (int r = 0; r < 4; r++) acc[i][j][r] = 0.f;

    for (int k0 = 0; k0 < KTOT; k0 += 64) {
        const unsigned short* Aseg = A0;
        const unsigned short* Bseg = B0;
        int kc = k0;
        if (MODE == 0) {
            const int seg = k0 >> 10;
            kc = k0 & 1023;
            if (seg == 1) Aseg = A1;   // xl * Wh
            if (seg == 2) Bseg = B1;   // xh * Wl
        }
        // stage A rows [w*32, w*32+32), B rows [w*16, w*16+16); 16B/lane
#pragma unroll
        for (int i = 0; i < 4; i++) {
            const int ar = w * 32 + i * 8 + r8;
            __builtin_amdgcn_global_load_lds(
                (glb_cvoid*)(Aseg + (size_t)(bm + ar) * 1024 + kc + csw),
                (lds_void*)(&Al[(w * 32 + i * 8) * 64]), 16, 0, 0);
        }
#pragma unroll
        for (int i = 0; i < 2; i++) {
            const int br = w * 16 + i * 8 + r8;
            __builtin_amdgcn_global_load_lds(
                (glb_cvoid*)(Bseg + (size_t)(bn + br) * 1024 + kc + csw),
                (lds_void*)(&Bl[(w * 16 + i * 8) * 64]), 16, 0, 0);
        }
        __syncthreads();   // staging visible (compiler drains vmcnt)

        bf16x8 af[4][2], bfr[2][2];
#pragma unroll
        for (int i = 0; i < 4; i++)
#pragma unroll
            for (int kk = 0; kk < 2; kk++)
                af[i][kk] = *reinterpret_cast<const bf16x8*>(
                    &Al[(wr * 64 + i * 16 + lr) * 64 +
                        (((kk * 4 + lg) ^ (lr & 7)) << 3)]);
#pragma unroll
        for (int j = 0; j < 2; j++)
#pragma unroll
            for (int kk = 0; kk < 2; kk++)
                bfr[j][kk] = *reinterpret_cast<const bf16x8*>(
                    &Bl[(wc * 32 + j * 16 + lr) * 64 +
                        (((kk * 4 + lg) ^ (lr & 7)) << 3)]);
#pragma unroll
        for (int kk = 0; kk < 2; kk++)
#pragma unroll
            for (int i = 0; i < 4; i++)
#pragma unroll
                for (int j = 0; j < 2; j++)
                    acc[i][j] = __builtin_amdgcn_mfma_f32_16x16x32_bf16(
                        af[i][kk], bfr[j][kk], acc[i][j], 0, 0, 0);
        __syncthreads();   // reads done before next-iter overwrite
    }

    // epilogue: C/D layout col = lane&15, row = (lane>>4)*4 + reg
#pragma unroll
    for (int i = 0; i < 4; i++) {
#pragma unroll
        for (int j = 0; j < 2; j++) {
#pragma unroll
            for (int r = 0; r < 4; r++) {
                const int row = bm + wr * 64 + i * 16 + lg * 4 + r;
                const int col = bn + wc * 32 + j * 16 + lr;
                float v = acc[i][j][r];
                if (MODE == 0) {
                    outF[(size_t)row * 1024 + col] = v;
                } else if (MODE == 1) {
                    v += bias[col];
                    const int hh = col >> 6, d = col & 63;
                    const int b = row >> 10, t = row & 1023;
                    // d-major: vtt[b,h,d,t]
                    outH[(((size_t)(b * 16 + hh) * 64 + d) * 1024) + t] =
                        f32_to_bf16(v);
                } else {
                    outF[(size_t)row * 1024 + col] = v + bias[col];
                }
            }
        }
    }
}

// ---------------------------------------------------------------------------
// Wave transform + l2norm.  One block per (b,t) row, 256 threads = (h,w).
// ---------------------------------------------------------------------------
__global__ __launch_bounds__(256)
void wave_norm(const float* __restrict__ raw,
               const float* __restrict__ bqf, const float* __restrict__ bkf,
               const float* __restrict__ bqp, const float* __restrict__ bkp,
               unsigned short* __restrict__ qn, unsigned short* __restrict__ kn)
{
    const int row = blockIdx.x;            // b*T + t
    const int b = row >> 10, t = row & 1023;
    const int tid = threadIdx.x;           // h*16 + w
    const float tf = (float)t;

    const float qf = raw[(size_t)row * 1024 + tid]        + bqf[tid];
    const float kf = raw[(size_t)row * 1024 + 256 + tid]  + bkf[tid];
    const float qp = raw[(size_t)row * 1024 + 512 + tid]  + bqp[tid];
    const float kp = raw[(size_t)row * 1024 + 768 + tid]  + bkp[tid];

    const float sq = sinf(fmaf(qf, tf, qp));
    const float sk = sinf(fmaf(kf, tf, kp));

    float nq = sq * sq, nk = sk * sk;
#pragma unroll
    for (int off = 8; off >= 1; off >>= 1) {
        nq += __shfl_xor(nq, off, 16);
        nk += __shfl_xor(nk, off, 16);
    }
    const float qv = sq * 2.0f / fmaxf(sqrtf(nq), 1e-12f);  // NW^0.25 = 2
    const float kv = sk * 2.0f / fmaxf(sqrtf(nk), 1e-12f);

    const int h = tid >> 4, ww = tid & 15;
    const size_t o = ((size_t)(b * 16 + h) * 1024 + t) * 16 + ww;
    qn[o] = f32_to_bf16(qv);
    kn[o] = f32_to_bf16(kv);
}

// ---------------------------------------------------------------------------
// MFMA causal linear attention, pair-balanced.
// grid (8, bh=64), 512 thr = 8 independent waves (no LDS, no barriers).
// Waves 0-3 own q-tile it=p (16 rows each); waves 4-7 own it=15-p -> every
// block does exactly 17 wave-tile-steps (uniform work, no tail).
// Per wave: register double-buffer of next-step K frags; V loads issued
// early (independent of the QK->elu->bpermute chain).
// ---------------------------------------------------------------------------
__global__ __launch_bounds__(512)
void wave_attn_mfma(const unsigned short* __restrict__ qn,
                    const unsigned short* __restrict__ kn,
                    const unsigned short* __restrict__ vtt,
                    const float* __restrict__ iscale,
                    unsigned short* __restrict__ y)
{
    const int p = blockIdx.x, bh = blockIdx.y;
    const int h = bh & 15, b = bh >> 4;
    const int tid = threadIdx.x;
    const int wq = tid >> 6;          // wave 0..7
    const int l = tid & 63;
    const int lt = l & 15;            // lane "column"
    const int gl = l >> 4;            // lane group 0..3
    const int it = (wq < 4) ? p : (15 - p);
    const int t0w = it * 64 + (wq & 3) * 16;
    const float scale = iscale[h];
    const int tmine = t0w + lt;       // t index this lane represents in S^T

    const bf16x8 zero8 = {0, 0, 0, 0, 0, 0, 0, 0};
    const f32x4 zf = {0.f, 0.f, 0.f, 0.f};
    const size_t kb = (size_t)bh * 1024;

    // Q fragment (B operand): col t = lt, k = w in [gl*8, gl*8+8), gl<2 real
    bf16x8 bq = zero8;
    if (gl < 2)
        bq = *reinterpret_cast<const bf16x8*>(&qn[(kb + t0w + lt) * 16 + gl * 8]);

    f32x4 o[4];
#pragma unroll
    for (int jd = 0; jd < 4; jd++) o[jd] = zf;

    // bpermute source lanes: (2*(gl&1)+c)*16 + lt, c=0,1 (byte addrs)
    const int addr0 = ((2 * (gl & 1)) * 16 + lt) * 4;
    const int addr1 = addr0 + 64;
    const bool hi = ((gl >> 1) & 1) != 0;

    // K tile 0 into current regs
    bf16x8 akc[4], akn[4];
#pragma unroll
    for (int js = 0; js < 4; js++) {
        akc[js] = zero8;
        if (gl < 2)
            akc[js] = *reinterpret_cast<const bf16x8*>(
                &kn[(kb + js * 16 + lt) * 16 + gl * 8]);
    }

    for (int is = 0; is <= it; is++) {
        const int s0 = is * 64;

        // ---- prefetch next K tile (double-buffer) ----
        if (is < it) {
#pragma unroll
            for (int js = 0; js < 4; js++) {
                akn[js] = zero8;
                if (gl < 2)
                    akn[js] = *reinterpret_cast<const bf16x8*>(
                        &kn[(kb + s0 + 64 + js * 16 + lt) * 16 + gl * 8]);
            }
        }
        // ---- V loads for current step, issued before the QK chain ----
        bf16x8 bv[2][4];
#pragma unroll
        for (int ks = 0; ks < 2; ks++)
#pragma unroll
            for (int jd = 0; jd < 4; jd++)
                bv[ks][jd] = *reinterpret_cast<const bf16x8*>(
                    &vtt[((size_t)(bh * 64 + jd * 16 + lt)) * 1024 +
                         s0 + ks * 32 + gl * 8]);

        // ---- QK^T: S^T[s 64][t 16] via 4 mfma (A = K-frag) ----
        f32x4 st[4];
#pragma unroll
        for (int js = 0; js < 4; js++)
            st[js] = __builtin_amdgcn_mfma_f32_16x16x32_bf16(
                akc[js], bq, zf, 0, 0, 0);

        // ---- elu+1, mask, pack to bf16 pairs ----
        // lane holds S[t = tmine][s = s0 + js*16 + gl*4 + r]
        int pk[4][2];
#pragma unroll
        for (int js = 0; js < 4; js++) {
            float pp[4];
#pragma unroll
            for (int r = 0; r < 4; r++) {
                const int s = s0 + js * 16 + gl * 4 + r;
                const float xv = st[js][r] * scale;
                const float phi = (xv > 0.f) ? (xv + 1.0f) : __expf(xv);
                pp[r] = (s <= tmine) ? phi : 0.f;
            }
            asm("v_cvt_pk_bf16_f32 %0, %1, %2"
                : "=v"(pk[js][0]) : "v"(pp[0]), "v"(pp[1]));
            asm("v_cvt_pk_bf16_f32 %0, %1, %2"
                : "=v"(pk[js][1]) : "v"(pp[2]), "v"(pp[3]));
        }

        // ---- in-wave transpose: gather A-frags of P (row t=lt, k=s) ----
        int rg[4][2][2];
#pragma unroll
        for (int js = 0; js < 4; js++)
#pragma unroll
            for (int sl = 0; sl < 2; sl++) {
                rg[js][sl][0] = __builtin_amdgcn_ds_bpermute(addr0, pk[js][sl]);
                rg[js][sl][1] = __builtin_amdgcn_ds_bpermute(addr1, pk[js][sl]);
            }

        // ---- PV: O[t][d] += P[t][s] V[s][d], K=64 = 2 steps ----
#pragma unroll
        for (int ks = 0; ks < 2; ks++) {
            i32x4 au;
#pragma unroll
            for (int c = 0; c < 2; c++)
#pragma unroll
                for (int sl = 0; sl < 2; sl++)
                    au[2 * c + sl] = hi ? rg[2 * ks + 1][sl][c]
                                        : rg[2 * ks][sl][c];
            const bf16x8 pa = __builtin_bit_cast(bf16x8, au);
#pragma unroll
            for (int jd = 0; jd < 4; jd++)
                o[jd] = __builtin_amdgcn_mfma_f32_16x16x32_bf16(
                    pa, bv[ks][jd], o[jd], 0, 0, 0);
        }

        // ---- rotate K double-buffer ----
#pragma unroll
        for (int js = 0; js < 4; js++) akc[js] = akn[js];
    }

    // ---- epilogue: /sqrt(t+1), write y[b,t,h*64+d] ----
#pragma unroll
    for (int r = 0; r < 4; r++) {
        const int t = t0w + gl * 4 + r;
        const float inv = rsqrtf((float)(t + 1));
#pragma unroll
        for (int jd = 0; jd < 4; jd++) {
            const int d = jd * 16 + lt;
            y[((size_t)b * 1024 + t) * 1024 + h * 64 + d] =
                f32_to_bf16(o[jd][r] * inv);
        }
    }
}

// ---------------------------------------------------------------------------
extern "C" void kernel_launch(void* const* d_in, const int* in_sizes, int n_in,
                              void* d_out, int out_size, void* d_ws, size_t ws_size,
                              hipStream_t stream)
{
    const float* x   = (const float*)d_in[0];
    const float* Wqf = (const float*)d_in[1];
    const float* bqf = (const float*)d_in[2];
    const float* Wkf = (const float*)d_in[3];
    const float* bkf = (const float*)d_in[4];
    const float* Wqp = (const float*)d_in[5];
    const float* bqp = (const float*)d_in[6];
    const float* Wkp = (const float*)d_in[7];
    const float* bkp = (const float*)d_in[8];
    const float* Wv  = (const float*)d_in[9];
    const float* bv  = (const float*)d_in[10];
    const float* Wo  = (const float*)d_in[11];
    const float* bo  = (const float*)d_in[12];
    const float* isc = (const float*)d_in[13];
    float* out = (float*)d_out;

    // workspace plan (38 MB, zero live-range overlaps — as round 4/5):
    //   [ 0,16) raw f32 (freq out)      -> after wave_norm: ybf bf16 [0,8)
    //   [16,24) xh bf16                    (live until v GEMM done)
    //   [24,32) xl bf16                 -> after freq GEMM: vtt bf16 [b,h,d,t]
    //   [32,34) WfH bf16                -> after freq GEMM: WvH, then WoH
    //   [34,36) WfL bf16                -> after freq GEMM: qn bf16
    //   [36,38) kn bf16
    char* ws = (char*)d_ws;
    float*          raw = (float*)(ws);
    unsigned short* ybf = (unsigned short*)(ws);
    unsigned short* xh  = (unsigned short*)(ws + (16u << 20));
    unsigned short* xl  = (unsigned short*)(ws + (24u << 20));
    unsigned short* vtt = (unsigned short*)(ws + (24u << 20));
    unsigned short* WfH = (unsigned short*)(ws + (32u << 20));
    unsigned short* WfL = (unsigned short*)(ws + (34u << 20));
    unsigned short* qn  = (unsigned short*)(ws + (34u << 20));
    unsigned short* kn  = (unsigned short*)(ws + (36u << 20));
    unsigned short* WvH = WfH;   // slot reuse after freq GEMM
    unsigned short* WoH = WfH;   // slot reuse after v GEMM

    // conversions for the split-precision freq GEMM
    split_bf16<<<4096, 256, 0, stream>>>(x, xh, xl, 1048576);
    split4_bf16<<<1024, 256, 0, stream>>>(Wqf, Wkf, Wqp, Wkp, WfH, WfL);

    // 1) freq/phase projections, split-precision K=3072 -> raw f32
    mfma_gemm<0><<<dim3(16, 32), 256, 0, stream>>>(
        xh, xl, WfH, WfL, nullptr, raw, nullptr);

    // 2) v projection -> vtt bf16 [b,h,d,t]  (overlays dead xl)
    split_bf16<<<1024, 256, 0, stream>>>(Wv, WvH, nullptr, 262144);
    mfma_gemm<1><<<dim3(16, 32), 256, 0, stream>>>(
        xh, nullptr, WvH, nullptr, bv, nullptr, vtt);

    // 3) sin + l2norm -> qn (overlays dead WfL) / kn
    wave_norm<<<4096, 256, 0, stream>>>(raw, bqf, bkf, bqp, bkp, qn, kn);

    // 4) MFMA causal linear attention (pair-balanced) -> ybf bf16
    wave_attn_mfma<<<dim3(8, 64), 512, 0, stream>>>(qn, kn, vtt, isc, ybf);

    // 5) output projection -> d_out f32
    split_bf16<<<1024, 256, 0, stream>>>(Wo, WoH, nullptr, 262144);
    mfma_gemm<2><<<dim3(16, 32), 256, 0, stream>>>(
        ybf, nullptr, WoH, nullptr, bo, out, nullptr);
}

// Round 7
// 227.154 us; speedup vs baseline: 2.8056x; 1.0035x over previous
//
#include <hip/hip_runtime.h>
#include <math.h>

typedef __attribute__((ext_vector_type(8))) short bf16x8;
typedef __attribute__((ext_vector_type(4))) float f32x4;
typedef __attribute__((ext_vector_type(4))) int i32x4;

typedef __attribute__((address_space(3))) void lds_void;
typedef __attribute__((address_space(1))) const void glb_cvoid;

__device__ __forceinline__ unsigned short f32_to_bf16(float f) {
    unsigned u = __float_as_uint(f);
    unsigned r = (u + 0x7FFFu + ((u >> 16) & 1u)) >> 16;
    return (unsigned short)r;
}
__device__ __forceinline__ float bf16_to_f32(unsigned short h) {
    return __uint_as_float(((unsigned)h) << 16);
}

// ---------------------------------------------------------------------------
// f32 -> bf16 hi (+ optional lo residual) converter. n4 = n/4 float4 groups.
// ---------------------------------------------------------------------------
__global__ __launch_bounds__(256)
void split_bf16(const float* __restrict__ src, unsigned short* __restrict__ hi,
                unsigned short* __restrict__ lo, int n4)
{
    const int i = blockIdx.x * 256 + threadIdx.x;
    if (i >= n4) return;
    float4 v = *reinterpret_cast<const float4*>(src + (size_t)i * 4);
    ushort4 h;
    h.x = f32_to_bf16(v.x); h.y = f32_to_bf16(v.y);
    h.z = f32_to_bf16(v.z); h.w = f32_to_bf16(v.w);
    *reinterpret_cast<ushort4*>(hi + (size_t)i * 4) = h;
    if (lo) {
        ushort4 l;
        l.x = f32_to_bf16(v.x - bf16_to_f32(h.x));
        l.y = f32_to_bf16(v.y - bf16_to_f32(h.y));
        l.z = f32_to_bf16(v.z - bf16_to_f32(h.z));
        l.w = f32_to_bf16(v.w - bf16_to_f32(h.w));
        *reinterpret_cast<ushort4*>(lo + (size_t)i * 4) = l;
    }
}

// Split of the four 256x1024 freq/phase weights (one launch):
//   WfH/WfL = [WqfH;WkfH]/[lo]  (512x1024, split)
//   WpH     = [WqpH;WkpH]       (512x1024, hi only — phase needs no residual)
__global__ __launch_bounds__(256)
void split4_bf16(const float* __restrict__ Wqf, const float* __restrict__ Wkf,
                 const float* __restrict__ Wqp, const float* __restrict__ Wkp,
                 unsigned short* __restrict__ WfH, unsigned short* __restrict__ WfL,
                 unsigned short* __restrict__ WpH)
{
    const int i = blockIdx.x * 256 + threadIdx.x;   // 0..262143 (float4 units)
    const int sel = i >> 16, j = i & 65535;
    const float* W = (sel == 0) ? Wqf : (sel == 1) ? Wkf : (sel == 2) ? Wqp : Wkp;
    float4 v = *reinterpret_cast<const float4*>(W + (size_t)j * 4);
    ushort4 h;
    h.x = f32_to_bf16(v.x); h.y = f32_to_bf16(v.y);
    h.z = f32_to_bf16(v.z); h.w = f32_to_bf16(v.w);
    const size_t o = (size_t)(sel & 1) * 262144 + (size_t)j * 4;
    if (sel < 2) {
        *reinterpret_cast<ushort4*>(WfH + o) = h;
        ushort4 l;
        l.x = f32_to_bf16(v.x - bf16_to_f32(h.x));
        l.y = f32_to_bf16(v.y - bf16_to_f32(h.y));
        l.z = f32_to_bf16(v.z - bf16_to_f32(h.z));
        l.w = f32_to_bf16(v.w - bf16_to_f32(h.w));
        *reinterpret_cast<ushort4*>(WfL + o) = l;
    } else {
        *reinterpret_cast<ushort4*>(WpH + o) = h;
    }
}

// XCD-aware bijective remap: all bn-tiles of an A-panel share one XCD
// (hw xcd ~ linear_id % 8).  Requires nbm % 8 == 0.
__device__ __forceinline__ void xcd_tiles(int& tm, int& tn) {
    const int L = blockIdx.x + gridDim.x * blockIdx.y;
    const int nbn = gridDim.x;
    const int q3 = L >> 3;
    tn = q3 % nbn;
    tm = (L & 7) + 8 * (q3 / nbn);
}

// ---------------------------------------------------------------------------
// Fused freq+phase projection GEMM + sin + l2norm -> qn/kn bf16 [b,h,t,w].
// Tile 64(M:t) x 64(N:col), BK=64, 256 thr = 4 waves (2x2), wave owns 32x32.
// K-segments: 0: xh*WfH, 1: xl*WfH, 2: xh*WfL  -> acc_f (split precision)
//             3: xh*WpH                        -> acc_p (plain bf16)
// cols 0..255 = qf/qp (h*16+w), 256..511 = kf/kp.
// Epilogue: f=acc_f+bf, p=acc_p+bp, s=sin(f*t+p), l2norm over the 16 w-lanes
// (one MFMA col-block == one head), *NW^0.25, write qn/kn.
// LDS XOR-swizzle both-sides (rule #21) as in mfma_gemm.
// ---------------------------------------------------------------------------
__global__ __launch_bounds__(256)
void freq_gemm_norm(const unsigned short* __restrict__ xh,
                    const unsigned short* __restrict__ xl,
                    const unsigned short* __restrict__ WfH,
                    const unsigned short* __restrict__ WfL,
                    const unsigned short* __restrict__ WpH,
                    const float* __restrict__ bqf, const float* __restrict__ bkf,
                    const float* __restrict__ bqp, const float* __restrict__ bkp,
                    unsigned short* __restrict__ qn, unsigned short* __restrict__ kn)
{
    __shared__ __attribute__((aligned(16))) unsigned short Al[64 * 64];
    __shared__ __attribute__((aligned(16))) unsigned short Bl[64 * 64];

    int tm, tn;
    xcd_tiles(tm, tn);                 // nbm=64, nbn=8
    const int bm = tm * 64, bn = tn * 64;

    const int tid = threadIdx.x;
    const int w = tid >> 6, l = tid & 63;
    const int wr = w >> 1, wc = w & 1;
    const int lr = l & 15, lg = l >> 4;
    const int r8 = l >> 3;             // staging row in 8-row chunk
    const int c8 = l & 7;              // 16B slot in 128B row
    const int csw = (c8 ^ r8) << 3;    // inverse-swizzled global col

    f32x4 accF[2][2], accP[2][2];
#pragma unroll
    for (int i = 0; i < 2; i++)
#pragma unroll
        for (int j = 0; j < 2; j++)
#pragma unroll
            for (int r = 0; r < 4; r++) { accF[i][j][r] = 0.f; accP[i][j][r] = 0.f; }

    for (int k0 = 0; k0 < 4096; k0 += 64) {
        const int seg = k0 >> 10;
        const int kc = k0 & 1023;
        const unsigned short* Aseg = (seg == 1) ? xl : xh;
        const unsigned short* Bseg = (seg <= 1) ? WfH : (seg == 2) ? WfL : WpH;

        // stage A rows [w*16, w*16+16), B rows [w*16, w*16+16); 16B/lane
#pragma unroll
        for (int i = 0; i < 2; i++) {
            __builtin_amdgcn_global_load_lds(
                (glb_cvoid*)(Aseg + (size_t)(bm + w * 16 + i * 8 + r8) * 1024 + kc + csw),
                (lds_void*)(&Al[(w * 16 + i * 8) * 64]), 16, 0, 0);
            __builtin_amdgcn_global_load_lds(
                (glb_cvoid*)(Bseg + (size_t)(bn + w * 16 + i * 8 + r8) * 1024 + kc + csw),
                (lds_void*)(&Bl[(w * 16 + i * 8) * 64]), 16, 0, 0);
        }
        __syncthreads();

        bf16x8 af[2][2], bfr[2][2];
#pragma unroll
        for (int i = 0; i < 2; i++)
#pragma unroll
            for (int kk = 0; kk < 2; kk++) {
                af[i][kk] = *reinterpret_cast<const bf16x8*>(
                    &Al[(wr * 32 + i * 16 + lr) * 64 + (((kk * 4 + lg) ^ (lr & 7)) << 3)]);
                bfr[i][kk] = *reinterpret_cast<const bf16x8*>(
                    &Bl[(wc * 32 + i * 16 + lr) * 64 + (((kk * 4 + lg) ^ (lr & 7)) << 3)]);
            }
        if (seg < 3) {
#pragma unroll
            for (int kk = 0; kk < 2; kk++)
#pragma unroll
                for (int i = 0; i < 2; i++)
#pragma unroll
                    for (int j = 0; j < 2; j++)
                        accF[i][j] = __builtin_amdgcn_mfma_f32_16x16x32_bf16(
                            af[i][kk], bfr[j][kk], accF[i][j], 0, 0, 0);
        } else {
#pragma unroll
            for (int kk = 0; kk < 2; kk++)
#pragma unroll
                for (int i = 0; i < 2; i++)
#pragma unroll
                    for (int j = 0; j < 2; j++)
                        accP[i][j] = __builtin_amdgcn_mfma_f32_16x16x32_bf16(
                            af[i][kk], bfr[j][kk], accP[i][j], 0, 0, 0);
        }
        __syncthreads();
    }

    // epilogue: C/D col = lane&15, row = lg*4 + reg
#pragma unroll
    for (int i = 0; i < 2; i++) {
#pragma unroll
        for (int j = 0; j < 2; j++) {
            const int col = bn + wc * 32 + j * 16 + lr;   // 0..511
            const bool isQ = col < 256;
            const int c = col & 255;
            const float bf = isQ ? bqf[c] : bkf[c];
            const float bp = isQ ? bqp[c] : bkp[c];
            unsigned short* dst = isQ ? qn : kn;
            const int h = c >> 4, ww = c & 15;
#pragma unroll
            for (int r = 0; r < 4; r++) {
                const int row = bm + wr * 32 + i * 16 + lg * 4 + r;
                const int b = row >> 10, t = row & 1023;
                const float f = accF[i][j][r] + bf;
                const float p = accP[i][j][r] + bp;
                const float s = sinf(fmaf(f, (float)t, p));
                float n2 = s * s;
#pragma unroll
                for (int off = 8; off >= 1; off >>= 1)
                    n2 += __shfl_xor(n2, off);
                const float val = s * 2.0f / fmaxf(sqrtf(n2), 1e-12f);
                dst[((size_t)(b * 16 + h) * 1024 + t) * 16 + ww] = f32_to_bf16(val);
            }
        }
    }
}

// ---------------------------------------------------------------------------
// bf16 MFMA GEMM: C[m,n] = sum_k A[m,k] * B[n,k]   (A,B row-major, K contig)
// Tile 128(M) x 64(N), BK=64, 256 threads = 4 waves (2x2), each wave 64x32.
// LDS XOR-swizzle both-sides (rule #21). XCD-aware tile remap.
// MODE 1 (v):    K=1024, +bias, writes vtt[b,h,d,t] bf16 (d-major!).
// MODE 2 (out):  K=1024, +bias, writes f32 (d_out).
// ---------------------------------------------------------------------------
template <int MODE>
__global__ __launch_bounds__(256)
void mfma_gemm(const unsigned short* __restrict__ A0,
               const unsigned short* __restrict__ B0,
               const float* __restrict__ bias,
               float* __restrict__ outF, unsigned short* __restrict__ outH)
{
    __shared__ __attribute__((aligned(16))) unsigned short Al[128 * 64];
    __shared__ __attribute__((aligned(16))) unsigned short Bl[64 * 64];

    int tm, tn;
    xcd_tiles(tm, tn);                 // nbm=32, nbn=gridDim.x
    const int bm = tm * 128, bn = tn * 64;

    const int tid = threadIdx.x;
    const int w = tid >> 6, l = tid & 63;
    const int wr = w >> 1, wc = w & 1;
    const int lr = l & 15, lg = l >> 4;
    const int r8 = l >> 3;
    const int c8 = l & 7;
    const int csw = (c8 ^ r8) << 3;

    f32x4 acc[4][2];
#pragma unroll
    for (int i = 0; i < 4; i++)
#pragma unroll
        for (int j = 0; j < 2; j++)
#pragma unroll
            for (int r = 0; r < 4; r++) acc[i][j][r] = 0.f;

    for (int k0 = 0; k0 < 1024; k0 += 64) {
#pragma unroll
        for (int i = 0; i < 4; i++) {
            __builtin_amdgcn_global_load_lds(
                (glb_cvoid*)(A0 + (size_t)(bm + w * 32 + i * 8 + r8) * 1024 + k0 + csw),
                (lds_void*)(&Al[(w * 32 + i * 8) * 64]), 16, 0, 0);
        }
#pragma unroll
        for (int i = 0; i < 2; i++) {
            __builtin_amdgcn_global_load_lds(
                (glb_cvoid*)(B0 + (size_t)(bn + w * 16 + i * 8 + r8) * 1024 + k0 + csw),
                (lds_void*)(&Bl[(w * 16 + i * 8) * 64]), 16, 0, 0);
        }
        __syncthreads();

        bf16x8 af[4][2], bfr[2][2];
#pragma unroll
        for (int i = 0; i < 4; i++)
#pragma unroll
            for (int kk = 0; kk < 2; kk++)
                af[i][kk] = *reinterpret_cast<const bf16x8*>(
                    &Al[(wr * 64 + i * 16 + lr) * 64 + (((kk * 4 + lg) ^ (lr & 7)) << 3)]);
#pragma unroll
        for (int j = 0; j < 2; j++)
#pragma unroll
            for (int kk = 0; kk < 2; kk++)
                bfr[j][kk] = *reinterpret_cast<const bf16x8*>(
                    &Bl[(wc * 32 + j * 16 + lr) * 64 + (((kk * 4 + lg) ^ (lr & 7)) << 3)]);
#pragma unroll
        for (int kk = 0; kk < 2; kk++)
#pragma unroll
            for (int i = 0; i < 4; i++)
#pragma unroll
                for (int j = 0; j < 2; j++)
                    acc[i][j] = __builtin_amdgcn_mfma_f32_16x16x32_bf16(
                        af[i][kk], bfr[j][kk], acc[i][j], 0, 0, 0);
        __syncthreads();
    }

#pragma unroll
    for (int i = 0; i < 4; i++) {
#pragma unroll
        for (int j = 0; j < 2; j++) {
#pragma unroll
            for (int r = 0; r < 4; r++) {
                const int row = bm + wr * 64 + i * 16 + lg * 4 + r;
                const int col = bn + wc * 32 + j * 16 + lr;
                float v = acc[i][j][r] + bias[col];
                if (MODE == 1) {
                    const int hh = col >> 6, d = col & 63;
                    const int b = row >> 10, t = row & 1023;
                    outH[(((size_t)(b * 16 + hh) * 64 + d) * 1024) + t] =
                        f32_to_bf16(v);
                } else {
                    outF[(size_t)row * 1024 + col] = v;
                }
            }
        }
    }
}

// ---------------------------------------------------------------------------
// MFMA causal linear attention, pair-balanced (unchanged from round 6).
// grid (8, bh=64), 512 thr = 8 independent waves (no LDS, no barriers).
// ---------------------------------------------------------------------------
__global__ __launch_bounds__(512)
void wave_attn_mfma(const unsigned short* __restrict__ qn,
                    const unsigned short* __restrict__ kn,
                    const unsigned short* __restrict__ vtt,
                    const float* __restrict__ iscale,
                    unsigned short* __restrict__ y)
{
    const int p = blockIdx.x, bh = blockIdx.y;
    const int h = bh & 15, b = bh >> 4;
    const int tid = threadIdx.x;
    const int wq = tid >> 6;          // wave 0..7
    const int l = tid & 63;
    const int lt = l & 15;
    const int gl = l >> 4;
    const int it = (wq < 4) ? p : (15 - p);
    const int t0w = it * 64 + (wq & 3) * 16;
    const float scale = iscale[h];
    const int tmine = t0w + lt;

    const bf16x8 zero8 = {0, 0, 0, 0, 0, 0, 0, 0};
    const f32x4 zf = {0.f, 0.f, 0.f, 0.f};
    const size_t kb = (size_t)bh * 1024;

    bf16x8 bq = zero8;
    if (gl < 2)
        bq = *reinterpret_cast<const bf16x8*>(&qn[(kb + t0w + lt) * 16 + gl * 8]);

    f32x4 o[4];
#pragma unroll
    for (int jd = 0; jd < 4; jd++) o[jd] = zf;

    const int addr0 = ((2 * (gl & 1)) * 16 + lt) * 4;
    const int addr1 = addr0 + 64;
    const bool hi = ((gl >> 1) & 1) != 0;

    bf16x8 akc[4], akn[4];
#pragma unroll
    for (int js = 0; js < 4; js++) {
        akc[js] = zero8;
        if (gl < 2)
            akc[js] = *reinterpret_cast<const bf16x8*>(
                &kn[(kb + js * 16 + lt) * 16 + gl * 8]);
    }

    for (int is = 0; is <= it; is++) {
        const int s0 = is * 64;

        if (is < it) {
#pragma unroll
            for (int js = 0; js < 4; js++) {
                akn[js] = zero8;
                if (gl < 2)
                    akn[js] = *reinterpret_cast<const bf16x8*>(
                        &kn[(kb + s0 + 64 + js * 16 + lt) * 16 + gl * 8]);
            }
        }
        bf16x8 bv[2][4];
#pragma unroll
        for (int ks = 0; ks < 2; ks++)
#pragma unroll
            for (int jd = 0; jd < 4; jd++)
                bv[ks][jd] = *reinterpret_cast<const bf16x8*>(
                    &vtt[((size_t)(bh * 64 + jd * 16 + lt)) * 1024 +
                         s0 + ks * 32 + gl * 8]);

        f32x4 st[4];
#pragma unroll
        for (int js = 0; js < 4; js++)
            st[js] = __builtin_amdgcn_mfma_f32_16x16x32_bf16(
                akc[js], bq, zf, 0, 0, 0);

        int pk[4][2];
#pragma unroll
        for (int js = 0; js < 4; js++) {
            float pp[4];
#pragma unroll
            for (int r = 0; r < 4; r++) {
                const int s = s0 + js * 16 + gl * 4 + r;
                const float xv = st[js][r] * scale;
                const float phi = (xv > 0.f) ? (xv + 1.0f) : __expf(xv);
                pp[r] = (s <= tmine) ? phi : 0.f;
            }
            asm("v_cvt_pk_bf16_f32 %0, %1, %2"
                : "=v"(pk[js][0]) : "v"(pp[0]), "v"(pp[1]));
            asm("v_cvt_pk_bf16_f32 %0, %1, %2"
                : "=v"(pk[js][1]) : "v"(pp[2]), "v"(pp[3]));
        }

        int rg[4][2][2];
#pragma unroll
        for (int js = 0; js < 4; js++)
#pragma unroll
            for (int sl = 0; sl < 2; sl++) {
                rg[js][sl][0] = __builtin_amdgcn_ds_bpermute(addr0, pk[js][sl]);
                rg[js][sl][1] = __builtin_amdgcn_ds_bpermute(addr1, pk[js][sl]);
            }

#pragma unroll
        for (int ks = 0; ks < 2; ks++) {
            i32x4 au;
#pragma unroll
            for (int c = 0; c < 2; c++)
#pragma unroll
                for (int sl = 0; sl < 2; sl++)
                    au[2 * c + sl] = hi ? rg[2 * ks + 1][sl][c]
                                        : rg[2 * ks][sl][c];
            const bf16x8 pa = __builtin_bit_cast(bf16x8, au);
#pragma unroll
            for (int jd = 0; jd < 4; jd++)
                o[jd] = __builtin_amdgcn_mfma_f32_16x16x32_bf16(
                    pa, bv[ks][jd], o[jd], 0, 0, 0);
        }

#pragma unroll
        for (int js = 0; js < 4; js++) akc[js] = akn[js];
    }

#pragma unroll
    for (int r = 0; r < 4; r++) {
        const int t = t0w + gl * 4 + r;
        const float inv = rsqrtf((float)(t + 1));
#pragma unroll
        for (int jd = 0; jd < 4; jd++) {
            const int d = jd * 16 + lt;
            y[((size_t)b * 1024 + t) * 1024 + h * 64 + d] =
                f32_to_bf16(o[jd][r] * inv);
        }
    }
}

// ---------------------------------------------------------------------------
extern "C" void kernel_launch(void* const* d_in, const int* in_sizes, int n_in,
                              void* d_out, int out_size, void* d_ws, size_t ws_size,
                              hipStream_t stream)
{
    const float* x   = (const float*)d_in[0];
    const float* Wqf = (const float*)d_in[1];
    const float* bqf = (const float*)d_in[2];
    const float* Wkf = (const float*)d_in[3];
    const float* bkf = (const float*)d_in[4];
    const float* Wqp = (const float*)d_in[5];
    const float* bqp = (const float*)d_in[6];
    const float* Wkp = (const float*)d_in[7];
    const float* bkp = (const float*)d_in[8];
    const float* Wv  = (const float*)d_in[9];
    const float* bv  = (const float*)d_in[10];
    const float* Wo  = (const float*)d_in[11];
    const float* bo  = (const float*)d_in[12];
    const float* isc = (const float*)d_in[13];
    float* out = (float*)d_out;

    // workspace plan (34 MB, zero live-range overlaps):
    //   [ 0, 8) ybf bf16 (attn out)
    //   [ 8,10) qn bf16   [10,12) kn bf16
    //   [12,13) WfH       [13,14) WfL       [14,15) WpH   (512x1024 each)
    //   [16,24) xh bf16   (dead after v GEMM)
    //   [24,32) xl bf16 -> vtt bf16 [b,h,d,t] after fused freq GEMM
    //   [32,34) WvH -> WoH (2 MB)
    char* ws = (char*)d_ws;
    unsigned short* ybf = (unsigned short*)(ws);
    unsigned short* qn  = (unsigned short*)(ws + ( 8u << 20));
    unsigned short* kn  = (unsigned short*)(ws + (10u << 20));
    unsigned short* WfH = (unsigned short*)(ws + (12u << 20));
    unsigned short* WfL = (unsigned short*)(ws + (13u << 20));
    unsigned short* WpH = (unsigned short*)(ws + (14u << 20));
    unsigned short* xh  = (unsigned short*)(ws + (16u << 20));
    unsigned short* xl  = (unsigned short*)(ws + (24u << 20));
    unsigned short* vtt = (unsigned short*)(ws + (24u << 20));
    unsigned short* WvH = (unsigned short*)(ws + (32u << 20));
    unsigned short* WoH = WvH;   // slot reuse after v GEMM

    // conversions
    split_bf16<<<4096, 256, 0, stream>>>(x, xh, xl, 1048576);
    split4_bf16<<<1024, 256, 0, stream>>>(Wqf, Wkf, Wqp, Wkp, WfH, WfL, WpH);

    // 1) fused freq(split K=3072) + phase(K=1024) GEMM + sin + l2norm
    freq_gemm_norm<<<dim3(8, 64), 256, 0, stream>>>(
        xh, xl, WfH, WfL, WpH, bqf, bkf, bqp, bkp, qn, kn);

    // 2) v projection -> vtt bf16 [b,h,d,t]  (overlays dead xl)
    split_bf16<<<1024, 256, 0, stream>>>(Wv, WvH, nullptr, 262144);
    mfma_gemm<1><<<dim3(16, 32), 256, 0, stream>>>(xh, WvH, bv, nullptr, vtt);

    // 3) MFMA causal linear attention (pair-balanced) -> ybf bf16
    wave_attn_mfma<<<dim3(8, 64), 512, 0, stream>>>(qn, kn, vtt, isc, ybf);

    // 4) output projection -> d_out f32
    split_bf16<<<1024, 256, 0, stream>>>(Wo, WoH, nullptr, 262144);
    mfma_gemm<2><<<dim3(16, 32), 256, 0, stream>>>(ybf, WoH, bo, out, nullptr);
}